// Round 4
// baseline (1411.956 us; speedup 1.0000x reference)
//
#include <hip/hip_runtime.h>

#define HH 64
#define WW 64
#define TT 100
#define CO 8
#define KS 6
#define LP 2
#define TS 16
#define HS 21          // TS + KS - 1
#define NS 441         // HS*HS halo sites
#define NTHR 256
#define NSLOT 3087     // NS * 7 float4 slots (max chunk = 7 f4 = 28 t)

__device__ __forceinline__ float stepu(float u, float s, float th, float wx) {
    // u = (u - s*th) + wx  -- exact reference association, no contraction
    return __fadd_rn(__fsub_rn(u, __fmul_rn(s, th)), wx);
}

#define FMA4(ACC, WD) \
    ACC.x = __fmaf_rn((WD), xv.x, ACC.x); \
    ACC.y = __fmaf_rn((WD), xv.y, ACC.y); \
    ACC.z = __fmaf_rn((WD), xv.z, ACC.z); \
    ACC.w = __fmaf_rn((WD), xv.w, ACC.w);

#define SCAN4(J) { \
    float u = ut[J], s = sprev[J]; unsigned m = 0u; \
    u = stepu(u, s, th, wx[J].x); s = (u > 0.f) ? 1.f : 0.f; m |= (u > 0.f) ? 1u : 0u; \
    u = stepu(u, s, th, wx[J].y); s = (u > 0.f) ? 1.f : 0.f; m |= (u > 0.f) ? 2u : 0u; \
    u = stepu(u, s, th, wx[J].z); s = (u > 0.f) ? 1.f : 0.f; m |= (u > 0.f) ? 4u : 0u; \
    u = stepu(u, s, th, wx[J].w); s = (u > 0.f) ? 1.f : 0.f; m |= (u > 0.f) ? 8u : 0u; \
    ut[J] = u; sprev[J] = s; cb[J] |= m << sh; }

// stage chunk [t0, t0+ngmax*4) into xs[tg*NS + site]; zero-fill padding sites.
__device__ __forceinline__ void stage_chunk(const float* __restrict__ xb,
                                            float4* __restrict__ xs,
                                            const int* __restrict__ offs,
                                            unsigned vbits, int tid,
                                            int t0, int ngmax)
{
#pragma unroll
    for (int k = 0; k < 13; ++k) {
        const int i2 = tid + (k << 8);
        if (i2 < NSLOT) {
            const int site = i2 / 7;
            const int tg   = i2 - site * 7;
            if (tg < ngmax) {
                float4 v = make_float4(0.f, 0.f, 0.f, 0.f);
                if ((vbits >> k) & 1u)
                    v = *(const float4*)(xb + offs[k] + t0);
                xs[tg * NS + site] = v;
            }
        }
    }
}

template<int T0, int NG>
__device__ __forceinline__ void compute_chunk(
    const float4* __restrict__ xs, const float4 (*__restrict__ wds4)[2],
    int rbase, float th, float* ut, float* sprev, unsigned* bw)
{
    unsigned cb[CO];
#pragma unroll
    for (int j = 0; j < CO; ++j) cb[j] = 0u;

#pragma unroll 1                 // rolled tg loop: body ~11 KB, I$-resident
    for (int tg = 0; tg < NG; ++tg) {
        const float4* xrow = xs + tg * NS + rbase;   // per-tg base; taps = imm offsets
        float4 wx[CO];
#pragma unroll
        for (int j = 0; j < CO; ++j) wx[j] = make_float4(0.f, 0.f, 0.f, 0.f);
#pragma unroll
        for (int kh = 0; kh < KS; ++kh) {
#pragma unroll
            for (int kw = 0; kw < KS; ++kw) {
                const float4 xv = xrow[kh * HS + kw];
                const float4 wa = wds4[kh * KS + kw][0];   // couts 0..3 (uniform b128)
                const float4 wb = wds4[kh * KS + kw][1];   // couts 4..7
                FMA4(wx[0], wa.x); FMA4(wx[1], wa.y);
                FMA4(wx[2], wa.z); FMA4(wx[3], wa.w);
                FMA4(wx[4], wb.x); FMA4(wx[5], wb.y);
                FMA4(wx[6], wb.z); FMA4(wx[7], wb.w);
            }
        }
        const int sh = tg * 4;
        SCAN4(0); SCAN4(1); SCAN4(2); SCAN4(3);
        SCAN4(4); SCAN4(5); SCAN4(6); SCAN4(7);
    }

    constexpr int W0 = T0 / 32;
    constexpr int S  = T0 % 32;
#pragma unroll
    for (int j = 0; j < CO; ++j) {
        bw[j * 4 + W0] |= cb[j] << S;
        if constexpr (S + NG * 4 > 32)
            bw[j * 4 + W0 + 1] |= cb[j] >> (32 - S);
    }
}

__global__ __launch_bounds__(256, 2)
void sconv2d_spike_kernel(const float* __restrict__ x,
                          const float* __restrict__ wgt,
                          const float* __restrict__ thresh,
                          float* __restrict__ out)
{
    __shared__ float4 xs[NSLOT];           // 49.4 KB (chunk buffer / flush alias)
    __shared__ float4 wds4[KS * KS][2];    // 1.2 KB: [tap][co-quartet]

    const int tid = threadIdx.x;
    for (int i = tid; i < KS * KS * CO; i += NTHR) {
        const int co  = i / (KS * KS);
        const int tap = i - co * (KS * KS);
        ((float*)wds4)[tap * 8 + co] = wgt[i];
    }
    const float th = thresh[0];

    // grid = 32 images x 16 tiles (4x4 of 16x16); 512 blocks = 2/CU exact
    const int blk = blockIdx.x;
    const int b   = blk >> 4;
    const int tb  = blk & 15;
    const int h0  = (tb >> 2) << 4;
    const int w0  = (tb & 3) << 4;
    const int r   = tid >> 4;
    const int c   = tid & 15;

    const float* xb = x + (size_t)b * (HH * WW * TT);

    // per-thread staging offsets (once; stage adds t0). Clamped coords, validity bit.
    int offs[13];
    unsigned vbits = 0u;
#pragma unroll
    for (int k = 0; k < 13; ++k) {
        const int i2 = tid + (k << 8);
        const int i3 = i2 < NSLOT ? i2 : 0;
        const int site = i3 / 7;
        const int tg   = i3 - site * 7;
        const int hr = site / HS;
        const int hc = site - hr * HS;
        const int hh = h0 - LP + hr;
        const int ww = w0 - LP + hc;
        const bool valid = ((unsigned)hh < (unsigned)HH) &&
                           ((unsigned)ww < (unsigned)WW) && (i2 < NSLOT);
        const int hcl = hh < 0 ? 0 : (hh > HH - 1 ? HH - 1 : hh);
        const int wcl = ww < 0 ? 0 : (ww > WW - 1 ? WW - 1 : ww);
        offs[k] = (hcl * WW + wcl) * TT + tg * 4;
        if (valid) vbits |= 1u << k;
    }

    float ut[CO], sprev[CO];
    unsigned bw[CO * 4];
#pragma unroll
    for (int j = 0; j < CO; ++j) { ut[j] = 0.f; sprev[j] = 0.f; }
#pragma unroll
    for (int i = 0; i < CO * 4; ++i) bw[i] = 0u;

    const int rbase = r * HS + c;

    stage_chunk(xb, xs, offs, vbits, tid, 0, 7);
    __syncthreads();
    compute_chunk< 0, 7>(xs, wds4, rbase, th, ut, sprev, bw);
    __syncthreads();

    stage_chunk(xb, xs, offs, vbits, tid, 28, 7);
    __syncthreads();
    compute_chunk<28, 7>(xs, wds4, rbase, th, ut, sprev, bw);
    __syncthreads();

    stage_chunk(xb, xs, offs, vbits, tid, 56, 7);
    __syncthreads();
    compute_chunk<56, 7>(xs, wds4, rbase, th, ut, sprev, bw);
    __syncthreads();

    stage_chunk(xb, xs, offs, vbits, tid, 84, 4);
    __syncthreads();
    compute_chunk<84, 4>(xs, wds4, rbase, th, ut, sprev, bw);
    __syncthreads();   // xs dead; alias as flush staging

    // ---- flush: stage all 8 couts' bit-words (stride 33: conflict-free writes),
    //      then fully-contiguous float4 store stream ----
    unsigned* stg = (unsigned*)xs;          // 256*33 words = 33.8 KB <= 49.4 KB
#pragma unroll
    for (int j = 0; j < CO; ++j) {
#pragma unroll
        for (int w = 0; w < 4; ++w)
            stg[tid * 33 + j * 4 + w] = bw[j * 4 + w];
    }
    __syncthreads();

    float* outb = out + (size_t)b * (CO * HH * WW * TT);
#pragma unroll 4
    for (int k = 0; k < 200; ++k) {
        const int idx = tid + (k << 8);       // 0..51199
        const int co  = idx / 6400;
        const int rem = idx - co * 6400;
        const int u   = rem / 25;             // site 0..255 (== computing tid)
        const int q   = rem - u * 25;
        const int tt  = q * 4;                // 0..96
        const unsigned bs = stg[u * 33 + co * 4 + (tt >> 5)] >> (tt & 31);
        float4 v;
        v.x = (float)( bs        & 1u);
        v.y = (float)((bs >> 1)  & 1u);
        v.z = (float)((bs >> 2)  & 1u);
        v.w = (float)((bs >> 3)  & 1u);
        *(float4*)(outb + (((size_t)co * HH + (h0 + (u >> 4))) * WW
                           + (w0 + (u & 15))) * TT + tt) = v;
    }
}

extern "C" void kernel_launch(void* const* d_in, const int* in_sizes, int n_in,
                              void* d_out, int out_size, void* d_ws, size_t ws_size,
                              hipStream_t stream) {
    const float* x      = (const float*)d_in[0];
    const float* wgt    = (const float*)d_in[1];
    const float* thresh = (const float*)d_in[2];
    float* out = (float*)d_out;
    (void)d_ws; (void)ws_size;

    sconv2d_spike_kernel<<<dim3(32 * 16), dim3(NTHR), 0, stream>>>(x, wgt, thresh, out);
}